// Round 6
// baseline (10296.217 us; speedup 1.0000x reference)
//
#include <hip/hip_runtime.h>
#include <math.h>

#define SEQ 128
#define B 64
#define NN 128
#define IN_DIM 64
#define HID 128
#define BNH (B*NN*HID)   // 1,048,576

typedef unsigned short u16;
typedef __bf16 bf16x8 __attribute__((ext_vector_type(8)));
typedef float f32x4 __attribute__((ext_vector_type(4)));

__device__ __forceinline__ u16 f2bf(float f) {
    union { float f; unsigned u; } x; x.f = f;
    unsigned r = x.u + 0x7fffu + ((x.u >> 16) & 1u);
    return (u16)(r >> 16);
}
__device__ __forceinline__ float bf2f(u16 b) {
    union { unsigned u; float f; } x; x.u = ((unsigned)b) << 16; return x.f;
}
__device__ __forceinline__ bf16x8 ld_frag(const u16* p) {   // 16B-aligned
    union { uint4 q; bf16x8 v; } u;
    u.q = *(const uint4*)p;
    return u.v;
}
__device__ __forceinline__ uint2 pack4(const f32x4& a) {
    uint2 pk;
    pk.x = (unsigned)f2bf(a[0]) | ((unsigned)f2bf(a[1]) << 16);
    pk.y = (unsigned)f2bf(a[2]) | ((unsigned)f2bf(a[3]) << 16);
    return pk;
}
__device__ __forceinline__ bf16x8 cvt8(const float* p) {
    float4 v0 = *(const float4*)p, v1 = *(const float4*)(p + 4);
    union { uint4 q; bf16x8 v; } t;
    t.q.x = (unsigned)f2bf(v0.x) | ((unsigned)f2bf(v0.y) << 16);
    t.q.y = (unsigned)f2bf(v0.z) | ((unsigned)f2bf(v0.w) << 16);
    t.q.z = (unsigned)f2bf(v1.x) | ((unsigned)f2bf(v1.y) << 16);
    t.q.w = (unsigned)f2bf(v1.z) | ((unsigned)f2bf(v1.w) << 16);
    return t.v;
}

// ---------------- one-time prep ----------------
__global__ void prep_A2_kernel(const float* __restrict__ S, u16* __restrict__ A2bf) {
    int idx = blockIdx.x * 256 + threadIdx.x;   // 16384
    int m = idx >> 7, n = idx & 127;
    A2bf[idx] = f2bf(S[idx]);
    float acc = 0.f;
    #pragma unroll 4
    for (int k = 0; k < 128; ++k) acc += S[m*128 + k] * S[k*128 + n];
    A2bf[16384 + idx] = f2bf(2.f*acc - (m == n ? 1.f : 0.f));
}

// frag-major A2: [kc(4)][g(16)][lane(64)][8]; mp=g*16+(lane&15), n=kc*32+(lane>>4)*8+j
__global__ void prep_A2f_kernel(const u16* __restrict__ A2bf, u16* __restrict__ A2f) {
    int idx = blockIdx.x * 256 + threadIdx.x;   // 32768
    int j = idx & 7, lane = (idx >> 3) & 63, g = (idx >> 9) & 15, kc = idx >> 13;
    int mp = g*16 + (lane & 15);
    int n  = kc*32 + (lane >> 4)*8 + j;
    A2f[idx] = A2bf[mp*128 + n];
}

// frag-major WT: [kc][cg(NO/16)][lane][8]; col=cg*16+(lane&15), k=kc*32+(lane>>4)*8+j
__global__ void prep_WTf_kernel(const float* __restrict__ W, u16* __restrict__ WTf,
                                int F, int NO) {
    int KK = 3 * F;
    int idx = blockIdx.x * 256 + threadIdx.x;
    if (idx >= NO * KK) return;
    int per = 512 * (NO/16);
    int kc = idx / per, rem = idx % per;
    int cg = rem >> 9, lane = (rem >> 3) & 63, j = idx & 7;
    int col = cg*16 + (lane & 15);
    int k = kc*32 + (lane >> 4)*8 + j;
    int m = k / F, f = k - m*F;
    WTf[idx] = f2bf(W[(size_t)(f*3 + m) * NO + col]);
}

__global__ void init_h_kernel(const float* __restrict__ h,
                              u16* __restrict__ hbf0, u16* __restrict__ h0T,
                              u16* __restrict__ hbf1, u16* __restrict__ h1T) {
    int i = blockIdx.x * 256 + threadIdx.x;   // 2*BNH
    int which = (i >= BNH);
    int j = which ? i - BNH : i;
    u16 v = f2bf(h[i]);
    int bn = j >> 7, col = j & 127;
    if (!which) { hbf0[j] = v; h0T[(size_t)col*8192 + bn] = v; }
    else        { hbf1[j] = v; h1T[(size_t)col*8192 + bn] = v; }
}

// =====================================================================
// Fused per-step body. One block = one (b, nh, layer).
// nh splits: gates u-half (each block computes r fully + its u-quarter),
//            cand N-half. Everything else block-local.
// LDS arena (u16, pitch F): catT[F][128] -> overlay xsL[256][F];
//   rhT[c<128][n] at xsL[c][FIN+n]; xsL2[node][f2] at xsL[128+node][FIN+f2].
// =====================================================================
template<int L>
__device__ __forceinline__ void step_body(
    int b, int nh,
    const float* __restrict__ xf,   // L0: inputs[t]
    const u16* __restrict__ hbX,    // L1: hbf0 (rb)  (x = prev h0)
    const u16* __restrict__ xT,     // L1: h0T (rb)
    const u16* __restrict__ hbH,    // own-layer hbf (rb)
    const u16* __restrict__ hTH,    // own-layer hT  (rb)
    const u16* __restrict__ A2f,
    const u16* __restrict__ WTg, const float* __restrict__ bg,
    const u16* __restrict__ WTc, const float* __restrict__ bc,
    u16* __restrict__ rhb, float* __restrict__ ub,
    const float* __restrict__ hfR, float* __restrict__ hfW,
    u16* __restrict__ hbfW, u16* __restrict__ hTW,
    float* __restrict__ out2,
    u16* smem)
{
    constexpr int FIN = L ? 128 : 64;
    constexpr int F   = L ? 256 : 192;
    constexpr int KK  = 3 * F;
    const int tid = threadIdx.x;
    const int lane = tid & 63, w = tid >> 6;
    const int l15 = lane & 15, l16 = lane >> 4;

    // ---- ph1: stage catT[f][128n] (XOR swz) ----
    if (L == 0) {
        for (int task = tid; task < 1024; task += 512) {   // x rows f<64 (transpose f32)
            int ng8 = task & 15, f = task >> 4, n0 = ng8*8, bn = b*NN + n0;
            union { uint4 q; u16 s[8]; } t;
            #pragma unroll
            for (int i = 0; i < 8; ++i) t.s[i] = f2bf(xf[(size_t)(bn + i)*IN_DIM + f]);
            *(uint4*)&smem[f*128 + (n0 ^ ((f & 7)*8))] = t.q;
        }
    }
    {
        const int R0 = L ? 0 : 64;
        const int NT = (F - R0) * 16;
        for (int task = tid; task < NT; task += 512) {     // hT-sourced rows (vectorized)
            int ng8 = task & 15, f = R0 + (task >> 4);
            const u16* src;
            if (L == 1) src = (f < 128) ? (xT + (size_t)f*8192) : (hTH + (size_t)(f - 128)*8192);
            else        src = hTH + (size_t)(f - 64)*8192;
            uint4 q = *(const uint4*)(src + (size_t)b*128 + ng8*8);
            *(uint4*)&smem[f*128 + ((ng8*8) ^ ((f & 7)*8))] = q;
        }
    }
    __syncthreads();

    // ---- ph2: cat diffusion D[f][mp] (full 256 mp, duplicated per nh) ----
    {
        constexpr int NFW = F / 32;
        const int mg2 = w & 3, f0w = (w >> 2) * (F/2);
        f32x4 dacc[NFW][4];
        #pragma unroll
        for (int ff = 0; ff < NFW; ++ff)
            #pragma unroll
            for (int mm = 0; mm < 4; ++mm) dacc[ff][mm] = (f32x4)(0.f);
        #pragma unroll
        for (int kc = 0; kc < 4; ++kc) {
            bf16x8 bfr[4];
            #pragma unroll
            for (int mm = 0; mm < 4; ++mm)
                bfr[mm] = ld_frag(A2f + (((size_t)kc*16 + mg2*4 + mm)*64 + lane)*8);
            #pragma unroll
            for (int ff = 0; ff < NFW; ++ff) {
                const int fr = f0w + ff*16 + l15;
                bf16x8 afr = ld_frag(&smem[fr*128 + ((kc*32 + l16*8) ^ ((fr & 7)*8))]);
                #pragma unroll
                for (int mm = 0; mm < 4; ++mm)
                    dacc[ff][mm] = __builtin_amdgcn_mfma_f32_16x16x32_bf16(afr, bfr[mm], dacc[ff][mm], 0, 0, 0);
            }
        }
        __syncthreads();   // catT dead; overlay xsL
        #pragma unroll
        for (int ff = 0; ff < NFW; ++ff) {
            const int f4 = f0w + ff*16 + l16*4;
            #pragma unroll
            for (int mm = 0; mm < 4; ++mm) {
                const int mp = mg2*64 + mm*16 + l15;
                *(uint2*)&smem[mp*F + (f4 ^ ((mp & 7)*8))] = pack4(dacc[ff][mm]);
            }
        }
    }
    __syncthreads();

    // ---- ph3: gates proj M=128 x N=192 (r full + u quarter) ----
    const int mg = w & 1, ng = w >> 1;     // node-half x 48-col chunk
    {
        f32x4 pacc[4][3];
        #pragma unroll
        for (int fi = 0; fi < 4; ++fi)
            #pragma unroll
            for (int gj = 0; gj < 3; ++gj) pacc[fi][gj] = (f32x4)(0.f);

        #pragma unroll
        for (int kc = 0; kc < KK/32; ++kc) {
            const int k = kc*32, m = k / F, fl = k - m*F;
            bf16x8 bb[3];
            #pragma unroll
            for (int gj = 0; gj < 3; ++gj) {
                const int c0 = ng*48 + gj*16;
                const int ca = (c0 < 128) ? c0 : 128 + nh*64 + (c0 - 128);
                bb[gj] = ld_frag(WTg + (((size_t)kc*16 + (ca >> 4))*64 + lane)*8);
            }
            #pragma unroll
            for (int fi = 0; fi < 4; ++fi) {
                const int node = mg*64 + fi*16 + l15;
                bf16x8 a;
                if (m == 0) {
                    const int bn = b*NN + node;
                    if (fl < FIN) {
                        if (L == 0) a = cvt8(xf + (size_t)bn*IN_DIM + fl + l16*8);
                        else        a = ld_frag(hbX + (size_t)bn*HID + fl + l16*8);
                    } else a = ld_frag(hbH + (size_t)bn*HID + (fl - FIN) + l16*8);
                } else {
                    const int mp = (m - 1)*128 + node;
                    a = ld_frag(&smem[mp*F + ((fl + l16*8) ^ ((mp & 7)*8))]);
                }
                #pragma unroll
                for (int gj = 0; gj < 3; ++gj)
                    pacc[fi][gj] = __builtin_amdgcn_mfma_f32_16x16x32_bf16(a, bb[gj], pacc[fi][gj], 0, 0, 0);
            }
        }
        __syncthreads();   // xsL reads done; safe to write rhT into dead space

        // epi-g: r -> rhb global + rhT LDS; u -> ub global
        #pragma unroll
        for (int fi = 0; fi < 4; ++fi) {
            const int node0 = mg*64 + fi*16 + l16*4;
            #pragma unroll
            for (int gj = 0; gj < 3; ++gj) {
                const int c0 = ng*48 + gj*16;
                if (c0 < 128) {
                    const int c = c0 + l15;
                    union { uint2 q; u16 s[4]; } pk;
                    #pragma unroll
                    for (int r = 0; r < 4; ++r) {
                        const int bn = b*NN + node0 + r;
                        const float v = pacc[fi][gj][r] + bg[c];
                        const float s = 1.f/(1.f + expf(-v));
                        const u16 rv = f2bf(s * bf2f(hbH[(size_t)bn*HID + c]));
                        pk.s[r] = rv;
                        rhb[(size_t)bn*HID + c] = rv;
                    }
                    *(uint2*)&smem[c*F + FIN + (node0 ^ ((c & 7)*8))] = pk.q;
                } else {
                    const int uc = nh*64 + (c0 - 128) + l15;
                    const float bcv = bg[128 + uc];
                    #pragma unroll
                    for (int r = 0; r < 4; ++r) {
                        const int bn = b*NN + node0 + r;
                        const float v = pacc[fi][gj][r] + bcv;
                        ub[(size_t)bn*HID + uc] = 1.f/(1.f + expf(-v));
                    }
                }
            }
        }
    }
    __syncthreads();   // rhT + rhb/ub visible

    // ---- cand proj M=128 x N=64 (nh quarter), K interleaved with rh-diffusion ----
    const int cmg = w & 1, cng = w >> 1;
    f32x4 cacc[4];
    #pragma unroll
    for (int fi = 0; fi < 4; ++fi) cacc[fi] = (f32x4)(0.f);

    // m=0 chunks (global operands)
    #pragma unroll
    for (int kc = 0; kc < F/32; ++kc) {
        const int fl = kc*32;
        bf16x8 bb = ld_frag(WTc + (((size_t)kc*8 + nh*4 + cng)*64 + lane)*8);
        #pragma unroll
        for (int fi = 0; fi < 4; ++fi) {
            const int node = cmg*64 + fi*16 + l15;
            const int bn = b*NN + node;
            bf16x8 a;
            if (fl < FIN) {
                if (L == 0) a = cvt8(xf + (size_t)bn*IN_DIM + fl + l16*8);
                else        a = ld_frag(hbX + (size_t)bn*HID + fl + l16*8);
            } else a = ld_frag(rhb + (size_t)bn*HID + (fl - FIN) + l16*8);
            cacc[fi] = __builtin_amdgcn_mfma_f32_16x16x32_bf16(a, bb, cacc[fi], 0, 0, 0);
        }
    }

    // slots: diffuse rh slot -> xsL2, then cand chunk m=slot+1
    #pragma unroll
    for (int slot = 0; slot < 2; ++slot) {
        f32x4 d2[4][2];
        #pragma unroll
        for (int ff = 0; ff < 4; ++ff)
            #pragma unroll
            for (int mm = 0; mm < 2; ++mm) d2[ff][mm] = (f32x4)(0.f);
        const int sf0 = (w & 1)*64, sn0 = (w >> 1)*32;
        #pragma unroll
        for (int kc = 0; kc < 4; ++kc) {
            bf16x8 bfr[2];
            #pragma unroll
            for (int mm = 0; mm < 2; ++mm) {
                const int g = slot*8 + ((sn0 + mm*16) >> 4);
                bfr[mm] = ld_frag(A2f + (((size_t)kc*16 + g)*64 + lane)*8);
            }
            #pragma unroll
            for (int ff = 0; ff < 4; ++ff) {
                const int c = sf0 + ff*16 + l15;
                bf16x8 afr = ld_frag(&smem[c*F + FIN + ((kc*32 + l16*8) ^ ((c & 7)*8))]);
                #pragma unroll
                for (int mm = 0; mm < 2; ++mm)
                    d2[ff][mm] = __builtin_amdgcn_mfma_f32_16x16x32_bf16(afr, bfr[mm], d2[ff][mm], 0, 0, 0);
            }
        }
        __syncthreads();   // prior xsL2 readers done
        #pragma unroll
        for (int ff = 0; ff < 4; ++ff) {
            const int f4 = sf0 + ff*16 + l16*4;
            #pragma unroll
            for (int mm = 0; mm < 2; ++mm) {
                const int node = sn0 + mm*16 + l15;
                *(uint2*)&smem[(128 + node)*F + FIN + (f4 ^ ((node & 7)*8))] = pack4(d2[ff][mm]);
            }
        }
        __syncthreads();
        #pragma unroll
        for (int kc = 0; kc < F/32; ++kc) {
            const int fl = kc*32;
            const int kcg = (slot + 1)*(F/32) + kc;
            bf16x8 bb = ld_frag(WTc + (((size_t)kcg*8 + nh*4 + cng)*64 + lane)*8);
            #pragma unroll
            for (int fi = 0; fi < 4; ++fi) {
                const int node = cmg*64 + fi*16 + l15;
                bf16x8 a;
                if (fl < FIN) {
                    const int mp = slot*128 + node;
                    a = ld_frag(&smem[mp*F + ((fl + l16*8) ^ ((mp & 7)*8))]);
                } else {
                    a = ld_frag(&smem[(128 + node)*F + FIN + (((fl - FIN) + l16*8) ^ ((node & 7)*8))]);
                }
                cacc[fi] = __builtin_amdgcn_mfma_f32_16x16x32_bf16(a, bb, cacc[fi], 0, 0, 0);
            }
        }
    }

    // ---- epi-c: GRU update ----
    const int col = nh*64 + cng*16 + l15;
    const float bcv = bc[col];
    #pragma unroll
    for (int fi = 0; fi < 4; ++fi) {
        const int node0 = cmg*64 + fi*16 + l16*4;
        union { uint2 q; u16 s[4]; } pk;
        #pragma unroll
        for (int r = 0; r < 4; ++r) {
            const int bn = b*NN + node0 + r;
            const float v = cacc[fi][r] + bcv;
            const float cnd = tanhf(v);
            const float uu = ub[(size_t)bn*HID + col];
            const float ho = hfR[(size_t)bn*HID + col];
            const float hn = uu*ho + (1.f - uu)*cnd;
            hfW[(size_t)bn*HID + col] = hn;
            const u16 hv = f2bf(hn);
            hbfW[(size_t)bn*HID + col] = hv;
            pk.s[r] = hv;
            if (L == 1) out2[(size_t)bn*HID + col] = hn;
        }
        *(uint2*)&hTW[(size_t)col*8192 + (size_t)b*128 + node0] = pk.q;
    }
}

__global__ __launch_bounds__(512, 2) void kStep(int zoff,
    const float* xf, const u16* A2f,
    const u16* hbf0r, const u16* h0Tr, const float* hf0r, float* hf0w, u16* hbf0w, u16* h0Tw,
    const u16* WTgf0, const float* bg0, const u16* WTcf0, const float* bc0, u16* rhb0, float* ub0,
    const u16* hbf1r, const u16* h1Tr, const float* hf1r, float* hf1w, u16* hbf1w, u16* h1Tw,
    const u16* WTgf1, const float* bg1, const u16* WTcf1, const float* bc1, u16* rhb1, float* ub1,
    float* out2)
{
    extern __shared__ u16 smem[];
    const int b = blockIdx.x, nh = blockIdx.y;
    if ((int)blockIdx.z + zoff == 0)
        step_body<0>(b, nh, xf, nullptr, nullptr, hbf0r, h0Tr, A2f,
                     WTgf0, bg0, WTcf0, bc0, rhb0, ub0,
                     hf0r, hf0w, hbf0w, h0Tw, nullptr, smem);
    else
        step_body<1>(b, nh, nullptr, hbf0r, h0Tr, hbf1r, h1Tr, A2f,
                     WTgf1, bg1, WTcf1, bc1, rhb1, ub1,
                     hf1r, hf1w, hbf1w, h1Tw, out2, smem);
}

extern "C" void kernel_launch(void* const* d_in, const int* in_sizes, int n_in,
                              void* d_out, int out_size, void* d_ws, size_t ws_size,
                              hipStream_t stream) {
    (void)in_sizes; (void)n_in; (void)out_size; (void)ws_size;
    const float* inputs = (const float*)d_in[0];
    const float* h_init = (const float*)d_in[1];
    const float* S      = (const float*)d_in[2];
    const float* Wg0 = (const float*)d_in[3];
    const float* bg0 = (const float*)d_in[4];
    const float* Wc0 = (const float*)d_in[5];
    const float* bc0 = (const float*)d_in[6];
    const float* Wg1 = (const float*)d_in[7];
    const float* bg1 = (const float*)d_in[8];
    const float* Wc1 = (const float*)d_in[9];
    const float* bc1 = (const float*)d_in[10];

    float* out = (float*)d_out;
    float* outputs = out + 2 * (size_t)BNH;

    char* ws = (char*)d_ws;
    u16* A2bf  = (u16*)ws;                      ws += 32768 * 2;
    u16* A2f   = (u16*)ws;                      ws += 32768 * 2;
    u16* WTgf0 = (u16*)ws;                      ws += 256*576 * 2;
    u16* WTcf0 = (u16*)ws;                      ws += 128*576 * 2;
    u16* WTgf1 = (u16*)ws;                      ws += 256*768 * 2;
    u16* WTcf1 = (u16*)ws;                      ws += 128*768 * 2;
    ws = (char*)(((size_t)ws + 255) & ~(size_t)255);
    u16* rhb0 = (u16*)ws;                       ws += (size_t)BNH * 2;
    u16* rhb1 = (u16*)ws;                       ws += (size_t)BNH * 2;
    float* ub0 = (float*)ws;                    ws += (size_t)BNH * 4;
    float* ub1 = (float*)ws;                    ws += (size_t)BNH * 4;
    float* hf0_[2]; u16* hbf0_[2]; u16* h0T_[2];
    float* hf1_[2]; u16* hbf1_[2]; u16* h1T_[2];
    for (int i = 0; i < 2; ++i) {
        hf0_[i]  = (float*)ws;                  ws += (size_t)BNH * 4;
        hf1_[i]  = (float*)ws;                  ws += (size_t)BNH * 4;
        hbf0_[i] = (u16*)ws;                    ws += (size_t)BNH * 2;
        hbf1_[i] = (u16*)ws;                    ws += (size_t)BNH * 2;
        h0T_[i]  = (u16*)ws;                    ws += (size_t)BNH * 2;
        h1T_[i]  = (u16*)ws;                    ws += (size_t)BNH * 2;
    }

    hipFuncSetAttribute((const void*)kStep, hipFuncAttributeMaxDynamicSharedMemorySize, 131072);

    // init: h0 -> parity-1 buffers, h1 -> parity-0 buffers
    hipMemcpyAsync(hf0_[1], h_init, (size_t)BNH * sizeof(float), hipMemcpyDeviceToDevice, stream);
    hipMemcpyAsync(hf1_[0], h_init + BNH, (size_t)BNH * sizeof(float), hipMemcpyDeviceToDevice, stream);
    init_h_kernel<<<(2*BNH + 255)/256, 256, 0, stream>>>(h_init, hbf0_[1], h0T_[1], hbf1_[0], h1T_[0]);
    prep_A2_kernel<<<64, 256, 0, stream>>>(S, A2bf);
    prep_A2f_kernel<<<128, 256, 0, stream>>>(A2bf, A2f);
    prep_WTf_kernel<<<(256*576 + 255)/256, 256, 0, stream>>>(Wg0, WTgf0, 192, 256);
    prep_WTf_kernel<<<(128*576 + 255)/256, 256, 0, stream>>>(Wc0, WTcf0, 192, 128);
    prep_WTf_kernel<<<(256*768 + 255)/256, 256, 0, stream>>>(Wg1, WTgf1, 256, 256);
    prep_WTf_kernel<<<(128*768 + 255)/256, 256, 0, stream>>>(Wc1, WTcf1, 256, 128);

    for (int tau = 0; tau <= SEQ; ++tau) {
        const int nz = (tau == 0 || tau == SEQ) ? 1 : 2;
        const int zoff = (tau == SEQ) ? 1 : 0;
        const int rb = (tau + 1) & 1, wb = tau & 1;
        const int tx = (tau < SEQ) ? tau : (SEQ - 1);
        const float* xt = inputs + (size_t)tx * B * NN * IN_DIM;
        float* out2 = outputs + (size_t)((tau > 0) ? tau - 1 : 0) * BNH;

        kStep<<<dim3(64, 2, nz), 512, 131072, stream>>>(zoff,
            xt, A2f,
            hbf0_[rb], h0T_[rb], hf0_[rb], hf0_[wb], hbf0_[wb], h0T_[wb],
            WTgf0, bg0, WTcf0, bc0, rhb0, ub0,
            hbf1_[rb], h1T_[rb], hf1_[rb], hf1_[wb], hbf1_[wb], h1T_[wb],
            WTgf1, bg1, WTcf1, bc1, rhb1, ub1,
            out2);
    }
    // final hidden: h0 written last at tau=127 (wb=1); h1 at tau=128 (wb=0)
    hipMemcpyAsync(out, hf0_[1], (size_t)BNH * sizeof(float), hipMemcpyDeviceToDevice, stream);
    hipMemcpyAsync(out + BNH, hf1_[0], (size_t)BNH * sizeof(float), hipMemcpyDeviceToDevice, stream);
}

// Round 7
// 7869.777 us; speedup vs baseline: 1.3083x; 1.3083x over previous
//
#include <hip/hip_runtime.h>
#include <math.h>

#define SEQ 128
#define B 64
#define NN 128
#define IN_DIM 64
#define HID 128
#define BNH (B*NN*HID)   // 1,048,576

typedef unsigned short u16;
typedef __bf16 bf16x8 __attribute__((ext_vector_type(8)));
typedef float f32x4 __attribute__((ext_vector_type(4)));

__device__ __forceinline__ u16 f2bf(float f) {
    union { float f; unsigned u; } x; x.f = f;
    unsigned r = x.u + 0x7fffu + ((x.u >> 16) & 1u);
    return (u16)(r >> 16);
}
__device__ __forceinline__ float bf2f(u16 b) {
    union { unsigned u; float f; } x; x.u = ((unsigned)b) << 16; return x.f;
}
__device__ __forceinline__ bf16x8 ld_frag(const u16* p) {   // 16B-aligned
    union { uint4 q; bf16x8 v; } u;
    u.q = *(const uint4*)p;
    return u.v;
}
__device__ __forceinline__ uint2 pack4(const f32x4& a) {
    uint2 pk;
    pk.x = (unsigned)f2bf(a[0]) | ((unsigned)f2bf(a[1]) << 16);
    pk.y = (unsigned)f2bf(a[2]) | ((unsigned)f2bf(a[3]) << 16);
    return pk;
}
__device__ __forceinline__ bf16x8 cvt8(const float* p) {
    float4 v0 = *(const float4*)p, v1 = *(const float4*)(p + 4);
    union { uint4 q; bf16x8 v; } t;
    t.q.x = (unsigned)f2bf(v0.x) | ((unsigned)f2bf(v0.y) << 16);
    t.q.y = (unsigned)f2bf(v0.z) | ((unsigned)f2bf(v0.w) << 16);
    t.q.z = (unsigned)f2bf(v1.x) | ((unsigned)f2bf(v1.y) << 16);
    t.q.w = (unsigned)f2bf(v1.z) | ((unsigned)f2bf(v1.w) << 16);
    return t.v;
}

// ---------------- one-time prep ----------------
__global__ void prep_A2_kernel(const float* __restrict__ S, u16* __restrict__ A2bf) {
    int idx = blockIdx.x * 256 + threadIdx.x;   // 16384
    int m = idx >> 7, n = idx & 127;
    A2bf[idx] = f2bf(S[idx]);
    float acc = 0.f;
    #pragma unroll 4
    for (int k = 0; k < 128; ++k) acc += S[m*128 + k] * S[k*128 + n];
    A2bf[16384 + idx] = f2bf(2.f*acc - (m == n ? 1.f : 0.f));
}

// frag-major A2: [kc(4)][g(16)][lane(64)][8]; mp=g*16+(lane&15), n=kc*32+(lane>>4)*8+j
__global__ void prep_A2f_kernel(const u16* __restrict__ A2bf, u16* __restrict__ A2f) {
    int idx = blockIdx.x * 256 + threadIdx.x;   // 32768
    int j = idx & 7, lane = (idx >> 3) & 63, g = (idx >> 9) & 15, kc = idx >> 13;
    int mp = g*16 + (lane & 15);
    int n  = kc*32 + (lane >> 4)*8 + j;
    A2f[idx] = A2bf[mp*128 + n];
}

// frag-major WT: [kc][cg(NO/16)][lane][8]; col=cg*16+(lane&15), k=kc*32+(lane>>4)*8+j
__global__ void prep_WTf_kernel(const float* __restrict__ W, u16* __restrict__ WTf,
                                int F, int NO) {
    int KK = 3 * F;
    int idx = blockIdx.x * 256 + threadIdx.x;
    if (idx >= NO * KK) return;
    int per = 512 * (NO/16);
    int kc = idx / per, rem = idx % per;
    int cg = rem >> 9, lane = (rem >> 3) & 63, j = idx & 7;
    int col = cg*16 + (lane & 15);
    int k = kc*32 + (lane >> 4)*8 + j;
    int m = k / F, f = k - m*F;
    WTf[idx] = f2bf(W[(size_t)(f*3 + m) * NO + col]);
}

__global__ void init_h_kernel(const float* __restrict__ h,
                              u16* __restrict__ hbf0, u16* __restrict__ h0T,
                              u16* __restrict__ hbf1, u16* __restrict__ h1T) {
    int i = blockIdx.x * 256 + threadIdx.x;   // 2*BNH
    int which = (i >= BNH);
    int j = which ? i - BNH : i;
    u16 v = f2bf(h[i]);
    int bn = j >> 7, col = j & 127;
    if (!which) { hbf0[j] = v; h0T[(size_t)col*8192 + bn] = v; }
    else        { hbf1[j] = v; h1T[(size_t)col*8192 + bn] = v; }
}

// =====================================================================
// kA: gates path. block = (b, nh gate-half, mh node-half, L). 256 thr, <=64KB LDS.
//  stage catT[f][128] -> 2-pass diffusion (its 128 mp rows) -> xsL overlay + xsgF
//  -> gates proj M=64 x N=128 -> epi (nh0: r, rh, rhbT; nh1: u)
// =====================================================================
template<int L>
__device__ __forceinline__ void stepA(
    int b, int nh, int mh,
    const float* __restrict__ xf, const u16* __restrict__ hbX, const u16* __restrict__ xT,
    const u16* __restrict__ hbH, const u16* __restrict__ hTH,
    const u16* __restrict__ A2f, const u16* __restrict__ WTg, const float* __restrict__ bg,
    u16* __restrict__ rhb, u16* __restrict__ rhbT, float* __restrict__ ub,
    u16* __restrict__ xsgF, u16* smem)
{
    constexpr int FIN = L ? 128 : 64;
    constexpr int F   = L ? 256 : 192;
    constexpr int KK  = 3 * F;
    constexpr int FH  = F / 2;
    constexpr int NF2 = F / 32;
    const int tid = threadIdx.x;
    const int lane = tid & 63, w = tid >> 6;     // 4 waves
    const int l15 = lane & 15, l16 = lane >> 4;

    // ---- stage catT[f][n] (pitch 128, XOR (f&7)*8) ----
    if (L == 0) {
        for (int task = tid; task < 1024; task += 256) {   // x rows f<64 (transpose f32)
            int ng8 = task & 15, f = task >> 4, n0 = ng8*8, bn = b*NN + n0;
            union { uint4 q; u16 s[8]; } t;
            #pragma unroll
            for (int i = 0; i < 8; ++i) t.s[i] = f2bf(xf[(size_t)(bn + i)*IN_DIM + f]);
            *(uint4*)&smem[f*128 + (n0 ^ ((f & 7)*8))] = t.q;
        }
    }
    {
        const int R0 = L ? 0 : 64;
        const int NT = (F - R0) * 16;
        for (int task = tid; task < NT; task += 256) {
            int ng8 = task & 15, f = R0 + (task >> 4);
            const u16* src;
            if (L == 1) src = (f < 128) ? (xT + (size_t)f*8192) : (hTH + (size_t)(f - 128)*8192);
            else        src = hTH + (size_t)(f - 64)*8192;
            uint4 q = *(const uint4*)(src + (size_t)b*128 + ng8*8);
            *(uint4*)&smem[f*128 + ((ng8*8) ^ ((f & 7)*8))] = q;
        }
    }
    __syncthreads();

    // ---- diffusion: D[f][r], r = local mp row in [0,128): node mh*64+(r&63), slot r>>6.
    // Two passes over f-halves; pass 0 = f-high writes fh-block 1, pass 1 = f-low writes fh-block 0.
    const int mq = w;
    #pragma unroll
    for (int p = 0; p < 2; ++p) {
        const int fbase = (p == 0) ? FH : 0;
        f32x4 dacc[NF2][2];
        #pragma unroll
        for (int ff = 0; ff < NF2; ++ff)
            #pragma unroll
            for (int mm = 0; mm < 2; ++mm) dacc[ff][mm] = (f32x4)(0.f);
        #pragma unroll
        for (int kc = 0; kc < 4; ++kc) {
            bf16x8 bfr[2];
            #pragma unroll
            for (int mm = 0; mm < 2; ++mm) {
                const int g = (mq >> 1)*8 + mh*4 + (mq & 1)*2 + mm;
                bfr[mm] = ld_frag(A2f + (((size_t)kc*16 + g)*64 + lane)*8);
            }
            #pragma unroll
            for (int ff = 0; ff < NF2; ++ff) {
                const int f = fbase + ff*16 + l15;
                bf16x8 afr = ld_frag(&smem[f*128 + ((kc*32 + l16*8) ^ ((f & 7)*8))]);
                #pragma unroll
                for (int mm = 0; mm < 2; ++mm)
                    dacc[ff][mm] = __builtin_amdgcn_mfma_f32_16x16x32_bf16(afr, bfr[mm], dacc[ff][mm], 0, 0, 0);
            }
        }
        __syncthreads();    // all reads of this f-half done before overwriting its arena region
        const int fh = (p == 0) ? 1 : 0;
        #pragma unroll
        for (int ff = 0; ff < NF2; ++ff) {
            const int f4 = fbase + ff*16 + l16*4;
            const int col = f4 - fbase;
            #pragma unroll
            for (int mm = 0; mm < 2; ++mm) {
                const int r = mq*32 + mm*16 + l15;
                uint2 pk = pack4(dacc[ff][mm]);
                *(uint2*)&smem[fh*16384 + r*128 + (col ^ ((r & 7)*8))] = pk;
                if (nh == 0 && f4 < FIN) {
                    const int slot = r >> 6, node = mh*64 + (r & 63);
                    size_t off = ((((size_t)b*2 + slot)*(FIN/32) + (f4 >> 5))*8 + (node >> 4))*512
                               + (((f4 >> 3) & 3)*16 + (node & 15))*8 + (f4 & 7);
                    *(uint2*)(xsgF + off) = pk;
                }
            }
        }
    }
    __syncthreads();

    // ---- gates proj: M=64 (its nodes) x N=128 (its gate half) x K=3F ----
    f32x4 pacc[4][2];
    #pragma unroll
    for (int fi = 0; fi < 4; ++fi)
        #pragma unroll
        for (int gj = 0; gj < 2; ++gj) pacc[fi][gj] = (f32x4)(0.f);

    #pragma unroll
    for (int kc = 0; kc < KK/32; ++kc) {
        const int k = kc*32, m = k / F, fIn = k - m*F;
        bf16x8 bb[2];
        #pragma unroll
        for (int gj = 0; gj < 2; ++gj) {
            const int cg = nh*8 + w*2 + gj;
            bb[gj] = ld_frag(WTg + (((size_t)kc*16 + cg)*64 + lane)*8);
        }
        #pragma unroll
        for (int fi = 0; fi < 4; ++fi) {
            const int node = mh*64 + fi*16 + l15;
            const int bn = b*NN + node;
            bf16x8 a;
            if (m == 0) {
                if (fIn < FIN) {
                    if (L == 0) a = cvt8(xf + (size_t)bn*IN_DIM + fIn + l16*8);
                    else        a = ld_frag(hbX + (size_t)bn*HID + fIn + l16*8);
                } else a = ld_frag(hbH + (size_t)bn*HID + (fIn - FIN) + l16*8);
            } else {
                const int r = (m - 1)*64 + fi*16 + l15;
                const int fh = (fIn >= FH) ? 1 : 0;
                const int col = fIn - fh*FH + l16*8;
                a = ld_frag(&smem[fh*16384 + r*128 + (col ^ ((r & 7)*8))]);
            }
            #pragma unroll
            for (int gj = 0; gj < 2; ++gj)
                pacc[fi][gj] = __builtin_amdgcn_mfma_f32_16x16x32_bf16(a, bb[gj], pacc[fi][gj], 0, 0, 0);
        }
    }
    // ---- epilogue ----
    #pragma unroll
    for (int fi = 0; fi < 4; ++fi) {
        const int node0 = mh*64 + fi*16 + l16*4;
        #pragma unroll
        for (int gj = 0; gj < 2; ++gj) {
            const int cl = (w*2 + gj)*16 + l15;
            if (nh == 0) {
                const float bcv = bg[cl];
                union { uint2 q; u16 s[4]; } pk;
                #pragma unroll
                for (int rr = 0; rr < 4; ++rr) {
                    const int bn = b*NN + node0 + rr;
                    const float v = pacc[fi][gj][rr] + bcv;
                    const float s = 1.f/(1.f + expf(-v));
                    const u16 rv = f2bf(s * bf2f(hbH[(size_t)bn*HID + cl]));
                    pk.s[rr] = rv;
                    rhb[(size_t)bn*HID + cl] = rv;
                }
                *(uint2*)&rhbT[(size_t)cl*8192 + (size_t)b*128 + node0] = pk.q;
            } else {
                const float bcv = bg[128 + cl];
                #pragma unroll
                for (int rr = 0; rr < 4; ++rr) {
                    const int bn = b*NN + node0 + rr;
                    const float v = pacc[fi][gj][rr] + bcv;
                    ub[(size_t)bn*HID + cl] = 1.f/(1.f + expf(-v));
                }
            }
        }
    }
}

// =====================================================================
// kB: cand path. block = (b, mh node-quarter, L). 256 thr, 16KB LDS, 2 syncs.
//  rh-diffusion reads rhbT straight from global (coalesced frags) -> xsL2
//  -> cand proj M=32 x N=128 -> fused GRU epilogue
// =====================================================================
template<int L>
__device__ __forceinline__ void stepB(
    int b, int mh,
    const float* __restrict__ xf, const u16* __restrict__ hbX,
    const u16* __restrict__ rhb, const u16* __restrict__ rhbT, const float* __restrict__ ub,
    const u16* __restrict__ xsgF, const u16* __restrict__ A2f,
    const u16* __restrict__ WTc, const float* __restrict__ bc,
    const float* __restrict__ hfR, float* __restrict__ hfW,
    u16* __restrict__ hbfW, u16* __restrict__ hTW,
    float* __restrict__ out2, u16* smem /* xsL2 [64][128] */)
{
    constexpr int FIN = L ? 128 : 64;
    constexpr int F   = L ? 256 : 192;
    constexpr int KK  = 3 * F;
    const int tid = threadIdx.x;
    const int lane = tid & 63, w = tid >> 6;
    const int l15 = lane & 15, l16 = lane >> 4;

    // ---- rh diffusion: D2[c][r2], r2 = (m-1)*32 + node-local in [0,64) ----
    f32x4 d2[4][2];
    #pragma unroll
    for (int ff = 0; ff < 4; ++ff)
        #pragma unroll
        for (int mm = 0; mm < 2; ++mm) d2[ff][mm] = (f32x4)(0.f);
    #pragma unroll
    for (int kc = 0; kc < 4; ++kc) {
        bf16x8 bfr[2];
        #pragma unroll
        for (int mm = 0; mm < 2; ++mm) {
            const int g = (w & 1)*8 + mh*2 + mm;
            bfr[mm] = ld_frag(A2f + (((size_t)kc*16 + g)*64 + lane)*8);
        }
        #pragma unroll
        for (int ff = 0; ff < 4; ++ff) {
            const int c = (w >> 1)*64 + ff*16 + l15;
            bf16x8 afr = ld_frag(rhbT + (size_t)c*8192 + (size_t)b*128 + kc*32 + l16*8);
            #pragma unroll
            for (int mm = 0; mm < 2; ++mm)
                d2[ff][mm] = __builtin_amdgcn_mfma_f32_16x16x32_bf16(afr, bfr[mm], d2[ff][mm], 0, 0, 0);
        }
    }
    #pragma unroll
    for (int ff = 0; ff < 4; ++ff) {
        const int c4 = (w >> 1)*64 + ff*16 + l16*4;
        #pragma unroll
        for (int mm = 0; mm < 2; ++mm) {
            const int r2 = (w & 1)*32 + mm*16 + l15;
            *(uint2*)&smem[r2*128 + (c4 ^ ((r2 & 7)*8))] = pack4(d2[ff][mm]);
        }
    }
    __syncthreads();

    // ---- cand proj M=32 x N=128 x K=3F ----
    f32x4 cacc[2][2];
    #pragma unroll
    for (int fi = 0; fi < 2; ++fi)
        #pragma unroll
        for (int gj = 0; gj < 2; ++gj) cacc[fi][gj] = (f32x4)(0.f);

    #pragma unroll
    for (int kc = 0; kc < KK/32; ++kc) {
        const int k = kc*32, m = k / F, fIn = k - m*F;
        bf16x8 bb[2];
        #pragma unroll
        for (int gj = 0; gj < 2; ++gj)
            bb[gj] = ld_frag(WTc + (((size_t)kc*8 + w*2 + gj)*64 + lane)*8);
        #pragma unroll
        for (int fi = 0; fi < 2; ++fi) {
            const int node = mh*32 + fi*16 + l15;
            const int bn = b*NN + node;
            bf16x8 a;
            if (m == 0) {
                if (fIn < FIN) {
                    if (L == 0) a = cvt8(xf + (size_t)bn*IN_DIM + fIn + l16*8);
                    else        a = ld_frag(hbX + (size_t)bn*HID + fIn + l16*8);
                } else a = ld_frag(rhb + (size_t)bn*HID + (fIn - FIN) + l16*8);
            } else if (fIn < FIN) {
                size_t off = ((((size_t)b*2 + (m - 1))*(FIN/32) + (fIn >> 5))*8 + (mh*2 + fi))*512
                           + (size_t)lane*8;
                a = ld_frag(xsgF + off);
            } else {
                const int r2 = (m - 1)*32 + fi*16 + l15;
                const int col = fIn - FIN + l16*8;
                a = ld_frag(&smem[r2*128 + (col ^ ((r2 & 7)*8))]);
            }
            #pragma unroll
            for (int gj = 0; gj < 2; ++gj)
                cacc[fi][gj] = __builtin_amdgcn_mfma_f32_16x16x32_bf16(a, bb[gj], cacc[fi][gj], 0, 0, 0);
        }
    }
    // ---- epilogue: GRU ----
    #pragma unroll
    for (int fi = 0; fi < 2; ++fi) {
        const int node0 = mh*32 + fi*16 + l16*4;
        #pragma unroll
        for (int gj = 0; gj < 2; ++gj) {
            const int cl = (w*2 + gj)*16 + l15;
            const float bcv = bc[cl];
            union { uint2 q; u16 s[4]; } pk;
            #pragma unroll
            for (int rr = 0; rr < 4; ++rr) {
                const int bn = b*NN + node0 + rr;
                const float v = cacc[fi][gj][rr] + bcv;
                const float cnd = tanhf(v);
                const float uu = ub[(size_t)bn*HID + cl];
                const float ho = hfR[(size_t)bn*HID + cl];
                const float hn = uu*ho + (1.f - uu)*cnd;
                hfW[(size_t)bn*HID + cl] = hn;
                const u16 hv = f2bf(hn);
                hbfW[(size_t)bn*HID + cl] = hv;
                pk.s[rr] = hv;
                if (L == 1) out2[(size_t)bn*HID + cl] = hn;
            }
            *(uint2*)&hTW[(size_t)cl*8192 + (size_t)b*128 + node0] = pk.q;
        }
    }
}

__global__ __launch_bounds__(256, 2) void kA(int zoff,
    const float* xf, const u16* A2f,
    const u16* hbf0r, const u16* h0Tr, const u16* hbf1r, const u16* h1Tr,
    const u16* WTgf0, const float* bg0, u16* rhb0, u16* rhbT0, float* ub0, u16* xsgF0,
    const u16* WTgf1, const float* bg1, u16* rhb1, u16* rhbT1, float* ub1, u16* xsgF1)
{
    extern __shared__ u16 smem[];
    const int b = blockIdx.x, nh = blockIdx.y >> 1, mh = blockIdx.y & 1;
    if ((int)blockIdx.z + zoff == 0)
        stepA<0>(b, nh, mh, xf, nullptr, nullptr, hbf0r, h0Tr, A2f,
                 WTgf0, bg0, rhb0, rhbT0, ub0, xsgF0, smem);
    else
        stepA<1>(b, nh, mh, nullptr, hbf0r, h0Tr, hbf1r, h1Tr, A2f,
                 WTgf1, bg1, rhb1, rhbT1, ub1, xsgF1, smem);
}

__global__ __launch_bounds__(256, 2) void kB(int zoff,
    const float* xf, const u16* A2f, const u16* hbf0r,
    const u16* rhb0, const u16* rhbT0, const float* ub0, const u16* xsgF0,
    const u16* WTcf0, const float* bc0,
    const float* hf0r, float* hf0w, u16* hbf0w, u16* h0Tw,
    const u16* rhb1, const u16* rhbT1, const float* ub1, const u16* xsgF1,
    const u16* WTcf1, const float* bc1,
    const float* hf1r, float* hf1w, u16* hbf1w, u16* h1Tw,
    float* out2)
{
    extern __shared__ u16 smem[];
    const int b = blockIdx.x, mh = blockIdx.y;
    if ((int)blockIdx.z + zoff == 0)
        stepB<0>(b, mh, xf, nullptr, rhb0, rhbT0, ub0, xsgF0, A2f, WTcf0, bc0,
                 hf0r, hf0w, hbf0w, h0Tw, nullptr, smem);
    else
        stepB<1>(b, mh, nullptr, hbf0r, rhb1, rhbT1, ub1, xsgF1, A2f, WTcf1, bc1,
                 hf1r, hf1w, hbf1w, h1Tw, out2, smem);
}

extern "C" void kernel_launch(void* const* d_in, const int* in_sizes, int n_in,
                              void* d_out, int out_size, void* d_ws, size_t ws_size,
                              hipStream_t stream) {
    (void)in_sizes; (void)n_in; (void)out_size; (void)ws_size;
    const float* inputs = (const float*)d_in[0];
    const float* h_init = (const float*)d_in[1];
    const float* S      = (const float*)d_in[2];
    const float* Wg0 = (const float*)d_in[3];
    const float* bg0 = (const float*)d_in[4];
    const float* Wc0 = (const float*)d_in[5];
    const float* bc0 = (const float*)d_in[6];
    const float* Wg1 = (const float*)d_in[7];
    const float* bg1 = (const float*)d_in[8];
    const float* Wc1 = (const float*)d_in[9];
    const float* bc1 = (const float*)d_in[10];

    float* out = (float*)d_out;
    float* outputs = out + 2 * (size_t)BNH;

    char* ws = (char*)d_ws;
    u16* A2bf  = (u16*)ws;                      ws += 32768 * 2;
    u16* A2f   = (u16*)ws;                      ws += 32768 * 2;
    u16* WTgf0 = (u16*)ws;                      ws += 256*576 * 2;
    u16* WTcf0 = (u16*)ws;                      ws += 128*576 * 2;
    u16* WTgf1 = (u16*)ws;                      ws += 256*768 * 2;
    u16* WTcf1 = (u16*)ws;                      ws += 128*768 * 2;
    ws = (char*)(((size_t)ws + 255) & ~(size_t)255);
    u16* xsgF0 = (u16*)ws;                      ws += (size_t)64*2*2*4096 * 2;  // 2MB
    u16* xsgF1 = (u16*)ws;                      ws += (size_t)64*2*4*4096 * 2;  // 4MB
    u16* rhb0  = (u16*)ws;                      ws += (size_t)BNH * 2;
    u16* rhb1  = (u16*)ws;                      ws += (size_t)BNH * 2;
    u16* rhbT0 = (u16*)ws;                      ws += (size_t)BNH * 2;
    u16* rhbT1 = (u16*)ws;                      ws += (size_t)BNH * 2;
    float* ub0 = (float*)ws;                    ws += (size_t)BNH * 4;
    float* ub1 = (float*)ws;                    ws += (size_t)BNH * 4;
    float* hf0_[2]; u16* hbf0_[2]; u16* h0T_[2];
    float* hf1_[2]; u16* hbf1_[2]; u16* h1T_[2];
    for (int i = 0; i < 2; ++i) {
        hf0_[i]  = (float*)ws;                  ws += (size_t)BNH * 4;
        hf1_[i]  = (float*)ws;                  ws += (size_t)BNH * 4;
        hbf0_[i] = (u16*)ws;                    ws += (size_t)BNH * 2;
        hbf1_[i] = (u16*)ws;                    ws += (size_t)BNH * 2;
        h0T_[i]  = (u16*)ws;                    ws += (size_t)BNH * 2;
        h1T_[i]  = (u16*)ws;                    ws += (size_t)BNH * 2;
    }

    hipFuncSetAttribute((const void*)kA, hipFuncAttributeMaxDynamicSharedMemorySize, 65536);
    hipFuncSetAttribute((const void*)kB, hipFuncAttributeMaxDynamicSharedMemorySize, 16384);

    // init: h0 -> parity-1 buffers, h1 -> parity-0 buffers
    hipMemcpyAsync(hf0_[1], h_init, (size_t)BNH * sizeof(float), hipMemcpyDeviceToDevice, stream);
    hipMemcpyAsync(hf1_[0], h_init + BNH, (size_t)BNH * sizeof(float), hipMemcpyDeviceToDevice, stream);
    init_h_kernel<<<(2*BNH + 255)/256, 256, 0, stream>>>(h_init, hbf0_[1], h0T_[1], hbf1_[0], h1T_[0]);
    prep_A2_kernel<<<64, 256, 0, stream>>>(S, A2bf);
    prep_A2f_kernel<<<128, 256, 0, stream>>>(A2bf, A2f);
    prep_WTf_kernel<<<(256*576 + 255)/256, 256, 0, stream>>>(Wg0, WTgf0, 192, 256);
    prep_WTf_kernel<<<(128*576 + 255)/256, 256, 0, stream>>>(Wc0, WTcf0, 192, 128);
    prep_WTf_kernel<<<(256*768 + 255)/256, 256, 0, stream>>>(Wg1, WTgf1, 256, 256);
    prep_WTf_kernel<<<(128*768 + 255)/256, 256, 0, stream>>>(Wc1, WTcf1, 256, 128);

    for (int tau = 0; tau <= SEQ; ++tau) {
        const int nz = (tau == 0 || tau == SEQ) ? 1 : 2;
        const int zoff = (tau == SEQ) ? 1 : 0;
        const int rb = (tau + 1) & 1, wb = tau & 1;
        const int tx = (tau < SEQ) ? tau : (SEQ - 1);
        const float* xt = inputs + (size_t)tx * B * NN * IN_DIM;
        float* out2 = outputs + (size_t)((tau > 0) ? tau - 1 : 0) * BNH;

        kA<<<dim3(64, 4, nz), 256, 65536, stream>>>(zoff,
            xt, A2f,
            hbf0_[rb], h0T_[rb], hbf1_[rb], h1T_[rb],
            WTgf0, bg0, rhb0, rhbT0, ub0, xsgF0,
            WTgf1, bg1, rhb1, rhbT1, ub1, xsgF1);
        kB<<<dim3(64, 4, nz), 256, 16384, stream>>>(zoff,
            xt, A2f, hbf0_[rb],
            rhb0, rhbT0, ub0, xsgF0, WTcf0, bc0,
            hf0_[rb], hf0_[wb], hbf0_[wb], h0T_[wb],
            rhb1, rhbT1, ub1, xsgF1, WTcf1, bc1,
            hf1_[rb], hf1_[wb], hbf1_[wb], h1T_[wb],
            out2);
    }
    // final hidden: h0 last written at tau=127 (wb=1); h1 at tau=128 (wb=0)
    hipMemcpyAsync(out, hf0_[1], (size_t)BNH * sizeof(float), hipMemcpyDeviceToDevice, stream);
    hipMemcpyAsync(out + BNH, hf1_[0], (size_t)BNH * sizeof(float), hipMemcpyDeviceToDevice, stream);
}